// Round 1
// baseline (1595.214 us; speedup 1.0000x reference)
//
#include <hip/hip_runtime.h>
#include <math.h>

#define BB 2
#define LL 2048
#define DD 1024
#define HH 16
#define DH 64
#define HID 4096
#define MROWS (BB*LL)   // 4096

// ---------------------------------------------------------------- LayerNorm
__global__ __launch_bounds__(256) void ln_kernel(const float* __restrict__ in,
                                                 const float* __restrict__ w,
                                                 const float* __restrict__ b,
                                                 float* __restrict__ out) {
    int row = blockIdx.x;
    const float* x = in + (size_t)row * DD;
    float* o = out + (size_t)row * DD;
    int t = threadIdx.x;                       // 256 threads, 4 floats each
    float4 v = reinterpret_cast<const float4*>(x)[t];
    float s  = v.x + v.y + v.z + v.w;
    float ss = v.x*v.x + v.y*v.y + v.z*v.z + v.w*v.w;
    #pragma unroll
    for (int off = 32; off > 0; off >>= 1) {
        s  += __shfl_down(s,  off, 64);
        ss += __shfl_down(ss, off, 64);
    }
    __shared__ float red[8];
    int wid = t >> 6, lane = t & 63;
    if (lane == 0) { red[wid] = s; red[4 + wid] = ss; }
    __syncthreads();
    if (t == 0) {
        float S  = red[0] + red[1] + red[2] + red[3];
        float SS = red[4] + red[5] + red[6] + red[7];
        float mean = S / DD;
        float var  = SS / DD - mean * mean;
        red[0] = mean;
        red[1] = rsqrtf(var + 1e-5f);
    }
    __syncthreads();
    float mean = red[0], rstd = red[1];
    float4 wv = reinterpret_cast<const float4*>(w)[t];
    float4 bv = reinterpret_cast<const float4*>(b)[t];
    float4 ov;
    ov.x = (v.x - mean) * rstd * wv.x + bv.x;
    ov.y = (v.y - mean) * rstd * wv.y + bv.y;
    ov.z = (v.z - mean) * rstd * wv.z + bv.z;
    ov.w = (v.w - mean) * rstd * wv.w + bv.w;
    reinterpret_cast<float4*>(o)[t] = ov;
}

// ---------------------------------------------------------------- GEMM fp32
// C[M,N] = epi(A[M,K] @ W[K,N] + bias) (+ res)
// EPI: 0 = none, 1 = exact GELU, 2 = + residual
template<int EPI>
__global__ __launch_bounds__(256) void gemm_kernel(
    const float* __restrict__ A,
    const float* __restrict__ W,
    const float* __restrict__ bias,
    const float* __restrict__ res,
    float* __restrict__ C,
    int M, int N, int K)
{
    const int BM = 64, BN = 64, BK = 16;
    __shared__ __align__(16) float As[BK][68];   // transposed, padded (align+bank)
    __shared__ __align__(16) float Bs[BK][BN];
    int bn = blockIdx.x * BN;
    int bm = blockIdx.y * BM;
    int t  = threadIdx.x;
    int tx = t & 15, ty = t >> 4;
    int ar = t >> 2, ak = (t & 3) * 4;           // A-load: row, k4
    int bk = t >> 4, bc = (t & 15) * 4;          // B-load: k, col4

    float acc[4][4] = {};

    for (int k0 = 0; k0 < K; k0 += BK) {
        float4 av = *reinterpret_cast<const float4*>(&A[(size_t)(bm + ar) * K + k0 + ak]);
        As[ak + 0][ar] = av.x;
        As[ak + 1][ar] = av.y;
        As[ak + 2][ar] = av.z;
        As[ak + 3][ar] = av.w;
        *reinterpret_cast<float4*>(&Bs[bk][bc]) =
            *reinterpret_cast<const float4*>(&W[(size_t)(k0 + bk) * N + bn + bc]);
        __syncthreads();
        #pragma unroll
        for (int kk = 0; kk < BK; ++kk) {
            float4 a4 = *reinterpret_cast<const float4*>(&As[kk][ty * 4]);
            float4 b4 = *reinterpret_cast<const float4*>(&Bs[kk][tx * 4]);
            float a[4] = {a4.x, a4.y, a4.z, a4.w};
            float b[4] = {b4.x, b4.y, b4.z, b4.w};
            #pragma unroll
            for (int i = 0; i < 4; ++i)
                #pragma unroll
                for (int j = 0; j < 4; ++j)
                    acc[i][j] = fmaf(a[i], b[j], acc[i][j]);
        }
        __syncthreads();
    }

    float4 b4 = *reinterpret_cast<const float4*>(&bias[bn + tx * 4]);
    float bia[4] = {b4.x, b4.y, b4.z, b4.w};
    #pragma unroll
    for (int i = 0; i < 4; ++i) {
        int row = bm + ty * 4 + i;
        float c[4];
        #pragma unroll
        for (int j = 0; j < 4; ++j) c[j] = acc[i][j] + bia[j];
        if (EPI == 1) {
            #pragma unroll
            for (int j = 0; j < 4; ++j)
                c[j] = 0.5f * c[j] * (1.0f + erff(c[j] * 0.70710678118654752f));
        }
        if (EPI == 2) {
            float4 r4 = *reinterpret_cast<const float4*>(&res[(size_t)row * N + bn + tx * 4]);
            c[0] += r4.x; c[1] += r4.y; c[2] += r4.z; c[3] += r4.w;
        }
        float4 o4 = {c[0], c[1], c[2], c[3]};
        *reinterpret_cast<float4*>(&C[(size_t)row * N + bn + tx * 4]) = o4;
    }
}

// ---------------------------------------------------------------- Attention
// Dilation-2 causal window attention == 2 independent causal sliding-window
// attentions (per parity) over compressed length 1024, window 128 (+self).
// 1 wave/block; each lane owns one compressed query (q,o in registers);
// K/V tiles staged in LDS, read as broadcast.
__global__ __launch_bounds__(64) void attn_kernel(
    const float* __restrict__ qkv,   // [B*L, 3D]
    float* __restrict__ o)           // [B*L, D]
{
    int qt = blockIdx.x;             // 0..15  (compressed q-tile of 64)
    int p  = blockIdx.y;             // parity
    int bh = blockIdx.z;             // 0..31
    int b = bh >> 4, h = bh & 15;
    int lane = threadIdx.x;

    const float scale = 0.125f;      // 1/sqrt(64)
    int tq = qt * 64 + lane;         // compressed query index
    int lq = 2 * tq + p;             // sequence position

    const float* qrow = qkv + (size_t)(b * LL + lq) * (3 * DD) + h * DH;
    float qreg[DH];
    #pragma unroll
    for (int d = 0; d < DH; d += 4) {
        float4 t4 = *reinterpret_cast<const float4*>(qrow + d);
        qreg[d]     = t4.x * scale;
        qreg[d + 1] = t4.y * scale;
        qreg[d + 2] = t4.z * scale;
        qreg[d + 3] = t4.w * scale;
    }

    __shared__ __align__(16) float Ks[64][DH];
    __shared__ __align__(16) float Vs[64][DH];

    float m = 0.f, lsum = 0.f;
    float acc[DH] = {};

    int kt0 = qt - 2; if (kt0 < 0) kt0 = 0;
    for (int kt = kt0; kt <= qt; ++kt) {
        int ck = kt * 64 + lane;                 // compressed key row this lane stages
        const float* kbase = qkv + (size_t)(b * LL + 2 * ck + p) * (3 * DD) + DD + h * DH;
        const float* vbase = kbase + DD;
        #pragma unroll
        for (int d = 0; d < DH; d += 4) {
            *reinterpret_cast<float4*>(&Ks[lane][d]) = *reinterpret_cast<const float4*>(kbase + d);
            *reinterpret_cast<float4*>(&Vs[lane][d]) = *reinterpret_cast<const float4*>(vbase + d);
        }
        __syncthreads();
        for (int j = 0; j < 64; ++j) {
            int cj = kt * 64 + j;
            float s = 0.f;
            #pragma unroll
            for (int d = 0; d < DH; ++d) s = fmaf(qreg[d], Ks[j][d], s);
            bool ok = (cj >= tq - 128) && (cj <= tq);
            s = ok ? s : -1e30f;
            if (s > m + 8.f) {                   // defer-max rescale (essentially never)
                float corr = __expf(m - s);
                lsum *= corr;
                #pragma unroll
                for (int d = 0; d < DH; ++d) acc[d] *= corr;
                m = s;
            }
            float pj = __expf(s - m);            // masked -> exp(-1e30)=0
            lsum += pj;
            #pragma unroll
            for (int d = 0; d < DH; ++d) acc[d] = fmaf(pj, Vs[j][d], acc[d]);
        }
        __syncthreads();
    }

    float inv = 1.f / lsum;
    float* orow = o + (size_t)(b * LL + lq) * DD + h * DH;
    #pragma unroll
    for (int d = 0; d < DH; d += 4) {
        float4 o4 = {acc[d] * inv, acc[d + 1] * inv, acc[d + 2] * inv, acc[d + 3] * inv};
        *reinterpret_cast<float4*>(orow + d) = o4;
    }
}

// ---------------------------------------------------------------- launch
extern "C" void kernel_launch(void* const* d_in, const int* in_sizes, int n_in,
                              void* d_out, int out_size, void* d_ws, size_t ws_size,
                              hipStream_t stream) {
    const float* x      = (const float*)d_in[0];
    const float* n1w    = (const float*)d_in[1];
    const float* n1b    = (const float*)d_in[2];
    const float* qkv_w  = (const float*)d_in[3];
    const float* qkv_b  = (const float*)d_in[4];
    const float* out_w  = (const float*)d_in[5];
    const float* out_b  = (const float*)d_in[6];
    const float* n2w    = (const float*)d_in[7];
    const float* n2b    = (const float*)d_in[8];
    const float* ffn_w1 = (const float*)d_in[9];
    const float* ffn_b1 = (const float*)d_in[10];
    const float* ffn_w2 = (const float*)d_in[11];
    const float* ffn_b2 = (const float*)d_in[12];

    float* out = (float*)d_out;
    float* ws  = (float*)d_ws;

    // layout (floats):
    //   [0, 12M)   qkv   — later overlaid by mid [0, 16M)
    //   [12M, 16M) o     — (dead by GEMM3)
    //   [16M, 20M) xn, then y
    float* qkv_buf = ws;
    float* o_buf   = ws + (size_t)12 * 1024 * 1024;
    float* xny     = ws + (size_t)16 * 1024 * 1024;
    float* mid     = ws;
    float* h       = out;            // d_out doubles as LN2 scratch

    // 1. xn = LN(x)
    ln_kernel<<<MROWS, 256, 0, stream>>>(x, n1w, n1b, xny);
    // 2. qkv = xn @ qkv_w + qkv_b
    gemm_kernel<0><<<dim3(3 * DD / 64, MROWS / 64), 256, 0, stream>>>(
        xny, qkv_w, qkv_b, nullptr, qkv_buf, MROWS, 3 * DD, DD);
    // 3. o = dilated-window attention(qkv)
    attn_kernel<<<dim3(16, 2, BB * HH), 64, 0, stream>>>(qkv_buf, o_buf);
    // 4. y = x + o @ out_w + out_b
    gemm_kernel<2><<<dim3(DD / 64, MROWS / 64), 256, 0, stream>>>(
        o_buf, out_w, out_b, x, xny, MROWS, DD, DD);
    // 5. h = LN(y)   (h lives in d_out)
    ln_kernel<<<MROWS, 256, 0, stream>>>(xny, n2w, n2b, h);
    // 6. mid = gelu(h @ ffn_w1 + ffn_b1)
    gemm_kernel<1><<<dim3(HID / 64, MROWS / 64), 256, 0, stream>>>(
        h, ffn_w1, ffn_b1, nullptr, mid, MROWS, HID, DD);
    // 7. out = y + mid @ ffn_w2 + ffn_b2
    gemm_kernel<2><<<dim3(DD / 64, MROWS / 64), 256, 0, stream>>>(
        mid, ffn_w2, ffn_b2, xny, out, MROWS, DD, HID);
}

// Round 2
// 592.104 us; speedup vs baseline: 2.6941x; 2.6941x over previous
//
#include <hip/hip_runtime.h>
#include <math.h>

#define BB 2
#define LL 2048
#define DD 1024
#define HH 16
#define DH 64
#define HID 4096
#define MROWS (BB*LL)   // 4096

typedef __attribute__((ext_vector_type(8))) short bf16x8;
typedef __attribute__((ext_vector_type(4))) float f32x4;

__device__ __forceinline__ unsigned short f2bf(float f) {
    unsigned u = __builtin_bit_cast(unsigned, f);
    unsigned r = u + 0x7fffu + ((u >> 16) & 1u);
    return (unsigned short)(r >> 16);
}

__device__ __forceinline__ void ldsload16(const void* g, void* l) {
    __builtin_amdgcn_global_load_lds(
        (const __attribute__((address_space(1))) unsigned int*)g,
        (__attribute__((address_space(3))) unsigned int*)l,
        16, 0, 0);
}

// ------------------------------------------------- weight convert+transpose
// in: fp32 [K][N] row-major  ->  out: bf16 [N][K] row-major
__global__ __launch_bounds__(256) void convT_kernel(const float* __restrict__ in,
                                                    unsigned short* __restrict__ out,
                                                    int K, int N) {
    __shared__ float tile[64][65];
    int kt = blockIdx.y << 6, nt = blockIdx.x << 6;
    int t = threadIdx.x;
    int tr = t >> 4;            // 0..15
    int tc = (t & 15) << 2;     // 0,4,...,60
    #pragma unroll
    for (int i = 0; i < 4; ++i) {
        float4 v = *reinterpret_cast<const float4*>(&in[(size_t)(kt + i*16 + tr) * N + nt + tc]);
        tile[i*16 + tr][tc+0] = v.x;
        tile[i*16 + tr][tc+1] = v.y;
        tile[i*16 + tr][tc+2] = v.z;
        tile[i*16 + tr][tc+3] = v.w;
    }
    __syncthreads();
    #pragma unroll
    for (int i = 0; i < 4; ++i) {
        int n = i*16 + tr;
        ushort4 o4;
        o4.x = f2bf(tile[tc+0][n]);
        o4.y = f2bf(tile[tc+1][n]);
        o4.z = f2bf(tile[tc+2][n]);
        o4.w = f2bf(tile[tc+3][n]);
        *reinterpret_cast<ushort4*>(&out[(size_t)(nt + n) * K + kt + tc]) = o4;
    }
}

// ---------------------------------------------------------------- LayerNorm
// fp32 in -> bf16 out
__global__ __launch_bounds__(256) void ln_kernel(const float* __restrict__ in,
                                                 const float* __restrict__ w,
                                                 const float* __restrict__ b,
                                                 unsigned short* __restrict__ out) {
    int row = blockIdx.x;
    const float* x = in + (size_t)row * DD;
    unsigned short* o = out + (size_t)row * DD;
    int t = threadIdx.x;
    float4 v = reinterpret_cast<const float4*>(x)[t];
    float s  = v.x + v.y + v.z + v.w;
    float ss = v.x*v.x + v.y*v.y + v.z*v.z + v.w*v.w;
    #pragma unroll
    for (int off = 32; off > 0; off >>= 1) {
        s  += __shfl_down(s,  off, 64);
        ss += __shfl_down(ss, off, 64);
    }
    __shared__ float red[8];
    int wid = t >> 6, lane = t & 63;
    if (lane == 0) { red[wid] = s; red[4 + wid] = ss; }
    __syncthreads();
    if (t == 0) {
        float S  = red[0] + red[1] + red[2] + red[3];
        float SS = red[4] + red[5] + red[6] + red[7];
        float mean = S / DD;
        float var  = SS / DD - mean * mean;
        red[0] = mean;
        red[1] = rsqrtf(var + 1e-5f);
    }
    __syncthreads();
    float mean = red[0], rstd = red[1];
    float4 wv = reinterpret_cast<const float4*>(w)[t];
    float4 bv = reinterpret_cast<const float4*>(b)[t];
    ushort4 ov;
    ov.x = f2bf((v.x - mean) * rstd * wv.x + bv.x);
    ov.y = f2bf((v.y - mean) * rstd * wv.y + bv.y);
    ov.z = f2bf((v.z - mean) * rstd * wv.z + bv.z);
    ov.w = f2bf((v.w - mean) * rstd * wv.w + bv.w);
    reinterpret_cast<ushort4*>(o)[t] = ov;
}

// ---------------------------------------------------------------- MFMA GEMM
// C[M,N] = epi(A[M,K](bf16) @ WT[N,K](bf16)^T + bias)
// EPI: 0 = fp32 out; 1 = GELU -> bf16 out; 2 = fp32 out + res
// LDS layout (fragment-linear, conflict-free): per 16-row(16-col) tile a 1KB
// block of [slot4][idx16] 16B units; both global_load_lds dest and
// ds_read_b128 frag reads are base + lane*16.
template<int EPI>
__global__ __launch_bounds__(256) void mgemm(
    const unsigned short* __restrict__ A,
    const unsigned short* __restrict__ WT,
    const float* __restrict__ bias,
    const float* res, void* Cv,
    int M, int N, int K)
{
    __shared__ __align__(16) unsigned char smem[16384];
    unsigned char* Asb = smem;          // 8KB: 8 mtiles x 1KB
    unsigned char* Bsb = smem + 8192;   // 8KB: 8 ntiles x 1KB

    int bn = blockIdx.x * 128, bm = blockIdx.y * 128;
    int t = threadIdx.x;
    int lane = t & 63, w = t >> 6;
    int wr = w >> 1, wc = w & 1;
    int l15 = lane & 15, l4 = lane >> 4;

    // stage sources: lane fetches [row = base + l15][k0 + 8*l4], 16B contiguous
    const unsigned short* Ap = A  + (size_t)(bm + w*32 + l15) * K + 8*l4;
    const unsigned short* Bp = WT + (size_t)(bn + w*32 + l15) * K + 8*l4;
    unsigned stoff = w*2048 + lane*16;

    f32x4 acc[4][4] = {};

    for (int k0 = 0; k0 < K; k0 += 32) {
        ldsload16(Ap,        Asb + stoff);
        ldsload16(Ap + 16*K, Asb + stoff + 1024);
        ldsload16(Bp,        Bsb + stoff);
        ldsload16(Bp + 16*K, Bsb + stoff + 1024);
        Ap += 32; Bp += 32;
        __syncthreads();
        bf16x8 af[4], bfr[4];
        #pragma unroll
        for (int m = 0; m < 4; ++m)
            af[m] = *reinterpret_cast<const bf16x8*>(Asb + (wr*4 + m)*1024 + lane*16);
        #pragma unroll
        for (int n = 0; n < 4; ++n)
            bfr[n] = *reinterpret_cast<const bf16x8*>(Bsb + (wc*4 + n)*1024 + lane*16);
        #pragma unroll
        for (int m = 0; m < 4; ++m)
            #pragma unroll
            for (int n = 0; n < 4; ++n)
                acc[m][n] = __builtin_amdgcn_mfma_f32_16x16x32_bf16(af[m], bfr[n], acc[m][n], 0, 0, 0);
        __syncthreads();
    }

    #pragma unroll
    for (int m = 0; m < 4; ++m) {
        int row0 = bm + wr*64 + m*16 + l4*4;
        #pragma unroll
        for (int n = 0; n < 4; ++n) {
            int col = bn + wc*64 + n*16 + l15;
            float bi = bias[col];
            #pragma unroll
            for (int r = 0; r < 4; ++r) {
                float v = acc[m][n][r] + bi;
                size_t idx = (size_t)(row0 + r) * N + col;
                if (EPI == 0) {
                    ((float*)Cv)[idx] = v;
                } else if (EPI == 2) {
                    ((float*)Cv)[idx] = v + res[idx];
                } else {
                    v = 0.5f * v * (1.0f + erff(v * 0.70710678118654752f));
                    ((unsigned short*)Cv)[idx] = f2bf(v);
                }
            }
        }
    }
}

// ---------------------------------------------------------------- Attention
// Dilation-2 causal window == 2 independent causal sliding-window attentions
// (per parity), compressed length 1024, window 128 (+self). fp32 compute,
// bf16 output.
__global__ __launch_bounds__(64) void attn_kernel(
    const float* __restrict__ qkv,      // [B*L, 3D] fp32
    unsigned short* __restrict__ o)     // [B*L, D] bf16
{
    int qt = blockIdx.x;             // 0..15
    int p  = blockIdx.y;             // parity
    int bh = blockIdx.z;             // 0..31
    int b = bh >> 4, h = bh & 15;
    int lane = threadIdx.x;

    const float scale = 0.125f;
    int tq = qt * 64 + lane;
    int lq = 2 * tq + p;

    const float* qrow = qkv + (size_t)(b * LL + lq) * (3 * DD) + h * DH;
    float qreg[DH];
    #pragma unroll
    for (int d = 0; d < DH; d += 4) {
        float4 t4 = *reinterpret_cast<const float4*>(qrow + d);
        qreg[d]     = t4.x * scale;
        qreg[d + 1] = t4.y * scale;
        qreg[d + 2] = t4.z * scale;
        qreg[d + 3] = t4.w * scale;
    }

    __shared__ __align__(16) float Ks[64][DH];
    __shared__ __align__(16) float Vs[64][DH];

    float m = 0.f, lsum = 0.f;
    float acc[DH] = {};

    int kt0 = qt - 2; if (kt0 < 0) kt0 = 0;
    for (int kt = kt0; kt <= qt; ++kt) {
        int ck = kt * 64 + lane;
        const float* kbase = qkv + (size_t)(b * LL + 2 * ck + p) * (3 * DD) + DD + h * DH;
        const float* vbase = kbase + DD;
        #pragma unroll
        for (int d = 0; d < DH; d += 4) {
            *reinterpret_cast<float4*>(&Ks[lane][d]) = *reinterpret_cast<const float4*>(kbase + d);
            *reinterpret_cast<float4*>(&Vs[lane][d]) = *reinterpret_cast<const float4*>(vbase + d);
        }
        __syncthreads();
        for (int j = 0; j < 64; ++j) {
            int cj = kt * 64 + j;
            float s = 0.f;
            #pragma unroll
            for (int d = 0; d < DH; ++d) s = fmaf(qreg[d], Ks[j][d], s);
            bool ok = (cj >= tq - 128) && (cj <= tq);
            s = ok ? s : -1e30f;
            if (s > m + 8.f) {
                float corr = __expf(m - s);
                lsum *= corr;
                #pragma unroll
                for (int d = 0; d < DH; ++d) acc[d] *= corr;
                m = s;
            }
            float pj = __expf(s - m);
            lsum += pj;
            #pragma unroll
            for (int d = 0; d < DH; ++d) acc[d] = fmaf(pj, Vs[j][d], acc[d]);
        }
        __syncthreads();
    }

    float inv = 1.f / lsum;
    unsigned short* orow = o + (size_t)(b * LL + lq) * DD + h * DH;
    #pragma unroll
    for (int d = 0; d < DH; d += 4) {
        ushort4 o4;
        o4.x = f2bf(acc[d]     * inv);
        o4.y = f2bf(acc[d + 1] * inv);
        o4.z = f2bf(acc[d + 2] * inv);
        o4.w = f2bf(acc[d + 3] * inv);
        *reinterpret_cast<ushort4*>(orow + d) = o4;
    }
}

// ---------------------------------------------------------------- launch
extern "C" void kernel_launch(void* const* d_in, const int* in_sizes, int n_in,
                              void* d_out, int out_size, void* d_ws, size_t ws_size,
                              hipStream_t stream) {
    const float* x      = (const float*)d_in[0];
    const float* n1w    = (const float*)d_in[1];
    const float* n1b    = (const float*)d_in[2];
    const float* qkv_w  = (const float*)d_in[3];
    const float* qkv_b  = (const float*)d_in[4];
    const float* out_w  = (const float*)d_in[5];
    const float* out_b  = (const float*)d_in[6];
    const float* n2w    = (const float*)d_in[7];
    const float* n2b    = (const float*)d_in[8];
    const float* ffn_w1 = (const float*)d_in[9];
    const float* ffn_b1 = (const float*)d_in[10];
    const float* ffn_w2 = (const float*)d_in[11];
    const float* ffn_b2 = (const float*)d_in[12];

    unsigned char* wsb = (unsigned char*)d_ws;
    const size_t MB = 1024 * 1024;

    // ws layout (80MB total):
    //  [0,48MB)   qkv fp32   -> overlay: mid bf16 [0,32), h bf16 [32,40)
    //  [48,56MB)  xn bf16    -> overlay: o bf16
    //  [56,80MB)  weights bf16 transposed
    float*          qkv_buf = (float*)wsb;
    unsigned short* mid     = (unsigned short*)wsb;
    unsigned short* hbuf    = (unsigned short*)(wsb + 32*MB);
    unsigned short* xn      = (unsigned short*)(wsb + 48*MB);
    unsigned short* o_b     = xn;                      // overlay, disjoint lifetime
    unsigned short* qkvT    = (unsigned short*)(wsb + 56*MB);
    unsigned short* outT    = qkvT + (size_t)3*1024*1024;
    unsigned short* w1T     = qkvT + (size_t)4*1024*1024;
    unsigned short* w2T     = qkvT + (size_t)8*1024*1024;
    float*          y       = (float*)d_out;           // d_out doubles as y

    // 0. weight convert+transpose  fp32[K][N] -> bf16[N][K]
    convT_kernel<<<dim3(3*DD/64, DD/64), 256, 0, stream>>>(qkv_w,  qkvT, DD,  3*DD);
    convT_kernel<<<dim3(DD/64,   DD/64), 256, 0, stream>>>(out_w,  outT, DD,  DD);
    convT_kernel<<<dim3(HID/64,  DD/64), 256, 0, stream>>>(ffn_w1, w1T,  DD,  HID);
    convT_kernel<<<dim3(DD/64,  HID/64), 256, 0, stream>>>(ffn_w2, w2T,  HID, DD);

    // 1. xn = LN(x)                    (bf16)
    ln_kernel<<<MROWS, 256, 0, stream>>>(x, n1w, n1b, xn);
    // 2. qkv = xn @ qkv_w + qkv_b      (fp32)
    mgemm<0><<<dim3(3*DD/128, MROWS/128), 256, 0, stream>>>(
        xn, qkvT, qkv_b, nullptr, qkv_buf, MROWS, 3*DD, DD);
    // 3. o = dilated-window attention  (bf16)
    attn_kernel<<<dim3(16, 2, BB*HH), 64, 0, stream>>>(qkv_buf, o_b);
    // 4. y = x + o @ out_w + out_b     (fp32, in d_out)
    mgemm<2><<<dim3(DD/128, MROWS/128), 256, 0, stream>>>(
        o_b, outT, out_b, x, y, MROWS, DD, DD);
    // 5. h = LN(y)                     (bf16)
    ln_kernel<<<MROWS, 256, 0, stream>>>(y, n2w, n2b, hbuf);
    // 6. mid = gelu(h @ ffn_w1 + b1)   (bf16)
    mgemm<1><<<dim3(HID/128, MROWS/128), 256, 0, stream>>>(
        hbuf, w1T, ffn_b1, nullptr, mid, MROWS, HID, DD);
    // 7. out = y + mid @ ffn_w2 + b2   (fp32, in-place over y)
    mgemm<2><<<dim3(DD/128, MROWS/128), 256, 0, stream>>>(
        mid, w2T, ffn_b2, y, y, MROWS, DD, HID);
}

// Round 3
// 454.117 us; speedup vs baseline: 3.5128x; 1.3039x over previous
//
#include <hip/hip_runtime.h>
#include <math.h>

#define BB 2
#define LL 2048
#define DD 1024
#define HH 16
#define DH 64
#define HID 4096
#define MROWS (BB*LL)   // 4096

typedef __attribute__((ext_vector_type(8))) short bf16x8;
typedef __attribute__((ext_vector_type(4))) float f32x4;

__device__ __forceinline__ unsigned short f2bf(float f) {
    unsigned u = __builtin_bit_cast(unsigned, f);
    unsigned r = u + 0x7fffu + ((u >> 16) & 1u);
    return (unsigned short)(r >> 16);
}

__device__ __forceinline__ void ldsload16(const void* g, void* l) {
    __builtin_amdgcn_global_load_lds(
        (const __attribute__((address_space(1))) unsigned int*)g,
        (__attribute__((address_space(3))) unsigned int*)l,
        16, 0, 0);
}

// ------------------------------------------------- weight convert+transpose
// in: fp32 [K][N] row-major  ->  out: bf16 [N][K] row-major
__global__ __launch_bounds__(256) void convT_kernel(const float* __restrict__ in,
                                                    unsigned short* __restrict__ out,
                                                    int K, int N) {
    __shared__ float tile[64][65];
    int kt = blockIdx.y << 6, nt = blockIdx.x << 6;
    int t = threadIdx.x;
    int tr = t >> 4;            // 0..15
    int tc = (t & 15) << 2;     // 0,4,...,60
    #pragma unroll
    for (int i = 0; i < 4; ++i) {
        float4 v = *reinterpret_cast<const float4*>(&in[(size_t)(kt + i*16 + tr) * N + nt + tc]);
        tile[i*16 + tr][tc+0] = v.x;
        tile[i*16 + tr][tc+1] = v.y;
        tile[i*16 + tr][tc+2] = v.z;
        tile[i*16 + tr][tc+3] = v.w;
    }
    __syncthreads();
    #pragma unroll
    for (int i = 0; i < 4; ++i) {
        int n = i*16 + tr;
        ushort4 o4;
        o4.x = f2bf(tile[tc+0][n]);
        o4.y = f2bf(tile[tc+1][n]);
        o4.z = f2bf(tile[tc+2][n]);
        o4.w = f2bf(tile[tc+3][n]);
        *reinterpret_cast<ushort4*>(&out[(size_t)(nt + n) * K + kt + tc]) = o4;
    }
}

// ---------------------------------------------------------------- LayerNorm
// fp32 in -> bf16 out
__global__ __launch_bounds__(256) void ln_kernel(const float* __restrict__ in,
                                                 const float* __restrict__ w,
                                                 const float* __restrict__ b,
                                                 unsigned short* __restrict__ out) {
    int row = blockIdx.x;
    const float* x = in + (size_t)row * DD;
    unsigned short* o = out + (size_t)row * DD;
    int t = threadIdx.x;
    float4 v = reinterpret_cast<const float4*>(x)[t];
    float s  = v.x + v.y + v.z + v.w;
    float ss = v.x*v.x + v.y*v.y + v.z*v.z + v.w*v.w;
    #pragma unroll
    for (int off = 32; off > 0; off >>= 1) {
        s  += __shfl_down(s,  off, 64);
        ss += __shfl_down(ss, off, 64);
    }
    __shared__ float red[8];
    int wid = t >> 6, lane = t & 63;
    if (lane == 0) { red[wid] = s; red[4 + wid] = ss; }
    __syncthreads();
    if (t == 0) {
        float S  = red[0] + red[1] + red[2] + red[3];
        float SS = red[4] + red[5] + red[6] + red[7];
        float mean = S / DD;
        float var  = SS / DD - mean * mean;
        red[0] = mean;
        red[1] = rsqrtf(var + 1e-5f);
    }
    __syncthreads();
    float mean = red[0], rstd = red[1];
    float4 wv = reinterpret_cast<const float4*>(w)[t];
    float4 bv = reinterpret_cast<const float4*>(b)[t];
    ushort4 ov;
    ov.x = f2bf((v.x - mean) * rstd * wv.x + bv.x);
    ov.y = f2bf((v.y - mean) * rstd * wv.y + bv.y);
    ov.z = f2bf((v.z - mean) * rstd * wv.z + bv.z);
    ov.w = f2bf((v.w - mean) * rstd * wv.w + bv.w);
    reinterpret_cast<ushort4*>(o)[t] = ov;
}

// ---------------------------------------------------------------- MFMA GEMM
// C[M,N] = epi(A[M,K](bf16) @ WT[N,K](bf16)^T + bias)
// EPI: 0 = fp32 out; 1 = GELU -> bf16 out; 2 = fp32 out + res
// 128x128 tile, BK=32, double-buffered LDS with counted vmcnt (loads for
// tile k+1 stay in flight across the barrier while tile k computes).
// Fragment-linear LDS: per 16-row tile a 1KB block; both global_load_lds
// dest and ds_read_b128 frag reads are base + lane*16 (conflict-free).
template<int EPI>
__global__ __launch_bounds__(256) void mgemm(
    const unsigned short* __restrict__ A,
    const unsigned short* __restrict__ WT,
    const float* __restrict__ bias,
    const float* res, void* Cv,
    int M, int N, int K, int nbx)
{
    __shared__ __align__(16) unsigned char smem[32768];   // 2 x (A 8KB + B 8KB)
    int bid = blockIdx.x;
    int nwg = gridDim.x;
    int cpx = nwg >> 3;                                   // all grids %8 == 0
    int swz = (bid & 7) * cpx + (bid >> 3);               // XCD-aware swizzle
    int bn = (swz % nbx) * 128;
    int bm = (swz / nbx) * 128;
    int t = threadIdx.x, lane = t & 63, w = t >> 6;
    int wr = w >> 1, wc = w & 1;
    int l15 = lane & 15, l4 = lane >> 4;

    const unsigned short* Ap = A  + (size_t)(bm + w*32 + l15) * K + 8*l4;
    const unsigned short* Bp = WT + (size_t)(bn + w*32 + l15) * K + 8*l4;
    unsigned stoff = w*2048 + lane*16;

    f32x4 acc[4][4] = {};
    int nk = K >> 5;

    // prologue: stage tile 0 -> buf0
    {
        unsigned char* bs = smem;
        ldsload16(Ap,        bs + stoff);
        ldsload16(Ap + 16*K, bs + stoff + 1024);
        ldsload16(Bp,        bs + 8192 + stoff);
        ldsload16(Bp + 16*K, bs + 8192 + stoff + 1024);
        Ap += 32; Bp += 32;
    }
    for (int k = 0; k < nk; ++k) {
        if (k + 1 < nk) {
            unsigned char* bs = smem + (((k + 1) & 1) << 14);
            ldsload16(Ap,        bs + stoff);
            ldsload16(Ap + 16*K, bs + stoff + 1024);
            ldsload16(Bp,        bs + 8192 + stoff);
            ldsload16(Bp + 16*K, bs + 8192 + stoff + 1024);
            Ap += 32; Bp += 32;
            asm volatile("s_waitcnt vmcnt(4)\ns_barrier" ::: "memory");
        } else {
            asm volatile("s_waitcnt vmcnt(0)\ns_barrier" ::: "memory");
        }
        unsigned char* Asb = smem + ((k & 1) << 14);
        unsigned char* Bsb = Asb + 8192;
        bf16x8 af[4], bfr[4];
        #pragma unroll
        for (int mm = 0; mm < 4; ++mm)
            af[mm] = *reinterpret_cast<const bf16x8*>(Asb + (wr*4 + mm)*1024 + lane*16);
        #pragma unroll
        for (int nn = 0; nn < 4; ++nn)
            bfr[nn] = *reinterpret_cast<const bf16x8*>(Bsb + (wc*4 + nn)*1024 + lane*16);
        #pragma unroll
        for (int mm = 0; mm < 4; ++mm)
            #pragma unroll
            for (int nn = 0; nn < 4; ++nn)
                acc[mm][nn] = __builtin_amdgcn_mfma_f32_16x16x32_bf16(af[mm], bfr[nn], acc[mm][nn], 0, 0, 0);
        asm volatile("s_waitcnt lgkmcnt(0)\ns_barrier" ::: "memory");
    }

    #pragma unroll
    for (int mm = 0; mm < 4; ++mm) {
        int row0 = bm + wr*64 + mm*16 + l4*4;
        #pragma unroll
        for (int nn = 0; nn < 4; ++nn) {
            int col = bn + wc*64 + nn*16 + l15;
            float bi = bias[col];
            #pragma unroll
            for (int r = 0; r < 4; ++r) {
                float v = acc[mm][nn][r] + bi;
                size_t idx = (size_t)(row0 + r) * N + col;
                if (EPI == 0) {
                    ((float*)Cv)[idx] = v;
                } else if (EPI == 2) {
                    ((float*)Cv)[idx] = v + res[idx];
                } else {
                    v = 0.5f * v * (1.0f + erff(v * 0.70710678118654752f));
                    ((unsigned short*)Cv)[idx] = f2bf(v);
                }
            }
        }
    }
}

// ---------------------------------------------------------------- Attention
// Dilation-2 causal window == 2 independent causal sliding-window attentions
// (per parity), compressed length 1024, window 128 (+self). fp32 compute,
// bf16 output. 2 waves/block split the key range (j<32 / j>=32) with a
// flash-style partial-softmax merge; 4-acc ILP in the score dot; LDS rows
// padded to 68 floats (stage writes 8-way instead of 64-way conflicts;
// in-loop reads are same-address broadcast = conflict-free).
__global__ __launch_bounds__(128) void attn_kernel(
    const float* __restrict__ qkv,      // [B*L, 3D] fp32
    unsigned short* __restrict__ o)     // [B*L, D] bf16
{
    __shared__ __align__(16) float Ks[64][68];
    __shared__ __align__(16) float Vs[64][68];

    int qt = blockIdx.x;             // 0..15  (compressed q-tile of 64)
    int p  = blockIdx.y;             // parity
    int bh = blockIdx.z;             // 0..31
    int b = bh >> 4, h = bh & 15;
    int t = threadIdx.x, w = t >> 6, lane = t & 63;

    const float scale = 0.125f;      // 1/sqrt(64)
    int tq = qt * 64 + lane;         // compressed query index
    int lq = 2 * tq + p;             // sequence position

    const float* qrow = qkv + (size_t)(b * LL + lq) * (3 * DD) + h * DH;
    float qreg[DH];
    #pragma unroll
    for (int d = 0; d < DH; d += 4) {
        float4 t4 = *reinterpret_cast<const float4*>(qrow + d);
        qreg[d]     = t4.x * scale;
        qreg[d + 1] = t4.y * scale;
        qreg[d + 2] = t4.z * scale;
        qreg[d + 3] = t4.w * scale;
    }

    float m = 0.f, lsum = 0.f;
    float acc[DH] = {};

    int kt0 = qt - 2; if (kt0 < 0) kt0 = 0;
    for (int kt = kt0; kt <= qt; ++kt) {
        int ck = kt * 64 + lane;                 // compressed key row this lane stages
        const float* src = qkv + (size_t)(b * LL + 2 * ck + p) * (3 * DD) + DD + (w ? DD : 0) + h * DH;
        float* dst = w ? &Vs[lane][0] : &Ks[lane][0];
        #pragma unroll
        for (int d = 0; d < DH; d += 4)
            *reinterpret_cast<float4*>(dst + d) = *reinterpret_cast<const float4*>(src + d);
        __syncthreads();
        for (int jj = 0; jj < 32; ++jj) {
            int j = w * 32 + jj;                 // this wave's key slice
            int cj = kt * 64 + j;
            const float* kr = &Ks[j][0];
            float s0 = 0.f, s1 = 0.f, s2 = 0.f, s3 = 0.f;
            #pragma unroll
            for (int d = 0; d < DH; d += 4) {
                s0 = fmaf(qreg[d],     kr[d],     s0);
                s1 = fmaf(qreg[d + 1], kr[d + 1], s1);
                s2 = fmaf(qreg[d + 2], kr[d + 2], s2);
                s3 = fmaf(qreg[d + 3], kr[d + 3], s3);
            }
            float s = (s0 + s1) + (s2 + s3);
            bool ok = (cj >= tq - 128) && (cj <= tq);
            s = ok ? s : -1e30f;
            if (s > m + 8.f) {                   // defer-max rescale (rare)
                float corr = __expf(m - s);
                lsum *= corr;
                #pragma unroll
                for (int d = 0; d < DH; ++d) acc[d] *= corr;
                m = s;
            }
            float pj = __expf(s - m);            // masked -> 0
            lsum += pj;
            const float* vr = &Vs[j][0];
            #pragma unroll
            for (int d = 0; d < DH; ++d) acc[d] = fmaf(pj, vr[d], acc[d]);
        }
        __syncthreads();
    }

    // flash-style merge of the two waves' partials (reuse Ks/Vs storage)
    float* mb  = &Ks[0][0];                      // [64][68] acc of wave1
    float* msl = &Vs[0][0];                      // m at [lane], l at [68+lane]
    if (w == 1) {
        #pragma unroll
        for (int d = 0; d < DH; d += 4) {
            float4 a4 = {acc[d], acc[d + 1], acc[d + 2], acc[d + 3]};
            *reinterpret_cast<float4*>(&mb[lane * 68 + d]) = a4;
        }
        msl[lane]      = m;
        msl[68 + lane] = lsum;
    }
    __syncthreads();
    if (w == 0) {
        float m1 = msl[lane], l1 = msl[68 + lane];
        float mx = fmaxf(m, m1);
        float c0 = __expf(m - mx), c1 = __expf(m1 - mx);
        float L  = lsum * c0 + l1 * c1;
        float inv = 1.f / L;
        unsigned short* orow = o + (size_t)(b * LL + lq) * DD + h * DH;
        #pragma unroll
        for (int d = 0; d < DH; d += 4) {
            float4 a1 = *reinterpret_cast<const float4*>(&mb[lane * 68 + d]);
            ushort4 o4;
            o4.x = f2bf((acc[d]     * c0 + a1.x * c1) * inv);
            o4.y = f2bf((acc[d + 1] * c0 + a1.y * c1) * inv);
            o4.z = f2bf((acc[d + 2] * c0 + a1.z * c1) * inv);
            o4.w = f2bf((acc[d + 3] * c0 + a1.w * c1) * inv);
            *reinterpret_cast<ushort4*>(orow + d) = o4;
        }
    }
}

// ---------------------------------------------------------------- launch
extern "C" void kernel_launch(void* const* d_in, const int* in_sizes, int n_in,
                              void* d_out, int out_size, void* d_ws, size_t ws_size,
                              hipStream_t stream) {
    const float* x      = (const float*)d_in[0];
    const float* n1w    = (const float*)d_in[1];
    const float* n1b    = (const float*)d_in[2];
    const float* qkv_w  = (const float*)d_in[3];
    const float* qkv_b  = (const float*)d_in[4];
    const float* out_w  = (const float*)d_in[5];
    const float* out_b  = (const float*)d_in[6];
    const float* n2w    = (const float*)d_in[7];
    const float* n2b    = (const float*)d_in[8];
    const float* ffn_w1 = (const float*)d_in[9];
    const float* ffn_b1 = (const float*)d_in[10];
    const float* ffn_w2 = (const float*)d_in[11];
    const float* ffn_b2 = (const float*)d_in[12];

    unsigned char* wsb = (unsigned char*)d_ws;
    const size_t MB = 1024 * 1024;

    // ws layout (80MB total):
    //  [0,48MB)   qkv fp32   -> overlay: mid bf16 [0,32), h bf16 [32,40)
    //  [48,56MB)  xn bf16    -> overlay: o bf16
    //  [56,80MB)  weights bf16 transposed
    float*          qkv_buf = (float*)wsb;
    unsigned short* mid     = (unsigned short*)wsb;
    unsigned short* hbuf    = (unsigned short*)(wsb + 32*MB);
    unsigned short* xn      = (unsigned short*)(wsb + 48*MB);
    unsigned short* o_b     = xn;                      // overlay, disjoint lifetime
    unsigned short* qkvT    = (unsigned short*)(wsb + 56*MB);
    unsigned short* outT    = qkvT + (size_t)3*1024*1024;
    unsigned short* w1T     = qkvT + (size_t)4*1024*1024;
    unsigned short* w2T     = qkvT + (size_t)8*1024*1024;
    float*          y       = (float*)d_out;           // d_out doubles as y

    // 0. weight convert+transpose  fp32[K][N] -> bf16[N][K]
    convT_kernel<<<dim3(3*DD/64, DD/64), 256, 0, stream>>>(qkv_w,  qkvT, DD,  3*DD);
    convT_kernel<<<dim3(DD/64,   DD/64), 256, 0, stream>>>(out_w,  outT, DD,  DD);
    convT_kernel<<<dim3(HID/64,  DD/64), 256, 0, stream>>>(ffn_w1, w1T,  DD,  HID);
    convT_kernel<<<dim3(DD/64,  HID/64), 256, 0, stream>>>(ffn_w2, w2T,  HID, DD);

    // 1. xn = LN(x)                    (bf16)
    ln_kernel<<<MROWS, 256, 0, stream>>>(x, n1w, n1b, xn);
    // 2. qkv = xn @ qkv_w + qkv_b      (fp32)
    mgemm<0><<<(3*DD/128)*(MROWS/128), 256, 0, stream>>>(
        xn, qkvT, qkv_b, nullptr, qkv_buf, MROWS, 3*DD, DD, 3*DD/128);
    // 3. o = dilated-window attention  (bf16)
    attn_kernel<<<dim3(16, 2, BB*HH), 128, 0, stream>>>(qkv_buf, o_b);
    // 4. y = x + o @ out_w + out_b     (fp32, in d_out)
    mgemm<2><<<(DD/128)*(MROWS/128), 256, 0, stream>>>(
        o_b, outT, out_b, x, y, MROWS, DD, DD, DD/128);
    // 5. h = LN(y)                     (bf16)
    ln_kernel<<<MROWS, 256, 0, stream>>>(y, n2w, n2b, hbuf);
    // 6. mid = gelu(h @ ffn_w1 + b1)   (bf16)
    mgemm<1><<<(HID/128)*(MROWS/128), 256, 0, stream>>>(
        hbuf, w1T, ffn_b1, nullptr, mid, MROWS, HID, DD, HID/128);
    // 7. out = y + mid @ ffn_w2 + b2   (fp32, in-place over y)
    mgemm<2><<<(DD/128)*(MROWS/128), 256, 0, stream>>>(
        mid, w2T, ffn_b2, y, y, MROWS, DD, HID, DD/128);
}

// Round 4
// 388.020 us; speedup vs baseline: 4.1112x; 1.1703x over previous
//
#include <hip/hip_runtime.h>
#include <math.h>

#define BB 2
#define LL 2048
#define DD 1024
#define HH 16
#define DH 64
#define HID 4096
#define MROWS (BB*LL)   // 4096

typedef __attribute__((ext_vector_type(8))) short bf16x8;
typedef __attribute__((ext_vector_type(4))) float f32x4;

__device__ __forceinline__ unsigned short f2bf(float f) {
    unsigned u = __builtin_bit_cast(unsigned, f);
    unsigned r = u + 0x7fffu + ((u >> 16) & 1u);
    return (unsigned short)(r >> 16);
}

__device__ __forceinline__ void ldsload16(const void* g, void* l) {
    __builtin_amdgcn_global_load_lds(
        (const __attribute__((address_space(1))) unsigned int*)g,
        (__attribute__((address_space(3))) unsigned int*)l,
        16, 0, 0);
}

// ------------------------------------------------- weight convert+transpose
// in: fp32 [K][N] row-major  ->  out: bf16 [N][K] row-major
__global__ __launch_bounds__(256) void convT_kernel(const float* __restrict__ in,
                                                    unsigned short* __restrict__ out,
                                                    int K, int N) {
    __shared__ float tile[64][65];
    int kt = blockIdx.y << 6, nt = blockIdx.x << 6;
    int t = threadIdx.x;
    int tr = t >> 4;            // 0..15
    int tc = (t & 15) << 2;     // 0,4,...,60
    #pragma unroll
    for (int i = 0; i < 4; ++i) {
        float4 v = *reinterpret_cast<const float4*>(&in[(size_t)(kt + i*16 + tr) * N + nt + tc]);
        tile[i*16 + tr][tc+0] = v.x;
        tile[i*16 + tr][tc+1] = v.y;
        tile[i*16 + tr][tc+2] = v.z;
        tile[i*16 + tr][tc+3] = v.w;
    }
    __syncthreads();
    #pragma unroll
    for (int i = 0; i < 4; ++i) {
        int n = i*16 + tr;
        ushort4 o4;
        o4.x = f2bf(tile[tc+0][n]);
        o4.y = f2bf(tile[tc+1][n]);
        o4.z = f2bf(tile[tc+2][n]);
        o4.w = f2bf(tile[tc+3][n]);
        *reinterpret_cast<ushort4*>(&out[(size_t)(nt + n) * K + kt + tc]) = o4;
    }
}

// ---------------------------------------------------------------- LayerNorm
// fp32 in -> bf16 out
__global__ __launch_bounds__(256) void ln_kernel(const float* __restrict__ in,
                                                 const float* __restrict__ w,
                                                 const float* __restrict__ b,
                                                 unsigned short* __restrict__ out) {
    int row = blockIdx.x;
    const float* x = in + (size_t)row * DD;
    unsigned short* o = out + (size_t)row * DD;
    int t = threadIdx.x;
    float4 v = reinterpret_cast<const float4*>(x)[t];
    float s  = v.x + v.y + v.z + v.w;
    float ss = v.x*v.x + v.y*v.y + v.z*v.z + v.w*v.w;
    #pragma unroll
    for (int off = 32; off > 0; off >>= 1) {
        s  += __shfl_down(s,  off, 64);
        ss += __shfl_down(ss, off, 64);
    }
    __shared__ float red[8];
    int wid = t >> 6, lane = t & 63;
    if (lane == 0) { red[wid] = s; red[4 + wid] = ss; }
    __syncthreads();
    if (t == 0) {
        float S  = red[0] + red[1] + red[2] + red[3];
        float SS = red[4] + red[5] + red[6] + red[7];
        float mean = S / DD;
        float var  = SS / DD - mean * mean;
        red[0] = mean;
        red[1] = rsqrtf(var + 1e-5f);
    }
    __syncthreads();
    float mean = red[0], rstd = red[1];
    float4 wv = reinterpret_cast<const float4*>(w)[t];
    float4 bv = reinterpret_cast<const float4*>(b)[t];
    ushort4 ov;
    ov.x = f2bf((v.x - mean) * rstd * wv.x + bv.x);
    ov.y = f2bf((v.y - mean) * rstd * wv.y + bv.y);
    ov.z = f2bf((v.z - mean) * rstd * wv.z + bv.z);
    ov.w = f2bf((v.w - mean) * rstd * wv.w + bv.w);
    reinterpret_cast<ushort4*>(o)[t] = ov;
}

// ---------------------------------------------------------------- MFMA GEMM
// C[M,N] = epi(A[M,K](bf16) @ WT[N,K](bf16)^T + bias)
// EPI: 1 = GELU -> bf16 out; 2 = fp32 out + res;
//      3 = qkv: Q/K bf16 row-major, V -> vt[b][h][p][d][ck] (transposed+parity)
// 128x128 tile, BK=32, TRIPLE-buffered LDS, 2-deep prefetch with counted
// vmcnt (tile k+1,k+2 loads stay in flight across barriers).
// Fragment-linear LDS: per 16-row tile a 1KB block; both global_load_lds
// dest and ds_read_b128 frag reads are base + lane*16 (conflict-free).
template<int EPI>
__global__ __launch_bounds__(256) void mgemm(
    const unsigned short* __restrict__ A,
    const unsigned short* __restrict__ WT,
    const float* __restrict__ bias,
    const float* res, void* Cv,
    unsigned short* __restrict__ vt,
    int M, int N, int K, int nbx)
{
    __shared__ __align__(16) unsigned char smem[49152];   // 3 x (A 8KB + B 8KB)
    int bid = blockIdx.x;
    int nwg = gridDim.x;
    int cpx = nwg >> 3;                                   // all grids %8 == 0
    int swz = (bid & 7) * cpx + (bid >> 3);               // XCD-aware swizzle
    int bn = (swz % nbx) * 128;
    int bm = (swz / nbx) * 128;
    int t = threadIdx.x, lane = t & 63, w = t >> 6;
    int wr = w >> 1, wc = w & 1;
    int l15 = lane & 15, l4 = lane >> 4;

    const unsigned short* Ap = A  + (size_t)(bm + w*32 + l15) * K + 8*l4;
    const unsigned short* Bp = WT + (size_t)(bn + w*32 + l15) * K + 8*l4;
    unsigned stoff = w*2048 + lane*16;

    f32x4 acc[4][4] = {};
    int nk = K >> 5;

    unsigned char* pb0 = smem;
    unsigned char* pb1 = smem + 16384;
    unsigned char* pb2 = smem + 32768;

    auto stage = [&](unsigned char* bs) {
        ldsload16(Ap,        bs + stoff);
        ldsload16(Ap + 16*K, bs + stoff + 1024);
        ldsload16(Bp,        bs + 8192 + stoff);
        ldsload16(Bp + 16*K, bs + 8192 + stoff + 1024);
        Ap += 32; Bp += 32;
    };

    stage(pb0);
    stage(pb1);

    for (int k = 0; k < nk; ++k) {
        if (k + 2 < nk) {
            stage(pb2);
            asm volatile("s_waitcnt vmcnt(8)\ns_barrier" ::: "memory");
        } else if (k + 2 == nk) {
            asm volatile("s_waitcnt vmcnt(4)\ns_barrier" ::: "memory");
        } else {
            asm volatile("s_waitcnt vmcnt(0)\ns_barrier" ::: "memory");
        }
        unsigned char* Asb = pb0;
        unsigned char* Bsb = pb0 + 8192;
        bf16x8 af[4], bfr[4];
        #pragma unroll
        for (int mm = 0; mm < 4; ++mm)
            af[mm] = *reinterpret_cast<const bf16x8*>(Asb + (wr*4 + mm)*1024 + lane*16);
        #pragma unroll
        for (int nn = 0; nn < 4; ++nn)
            bfr[nn] = *reinterpret_cast<const bf16x8*>(Bsb + (wc*4 + nn)*1024 + lane*16);
        #pragma unroll
        for (int mm = 0; mm < 4; ++mm)
            #pragma unroll
            for (int nn = 0; nn < 4; ++nn)
                acc[mm][nn] = __builtin_amdgcn_mfma_f32_16x16x32_bf16(af[mm], bfr[nn], acc[mm][nn], 0, 0, 0);
        asm volatile("s_waitcnt lgkmcnt(0)\ns_barrier" ::: "memory");
        unsigned char* tp = pb0; pb0 = pb1; pb1 = pb2; pb2 = tp;
    }

    bool isv = (EPI == 3) && (bn >= 2048);
    #pragma unroll
    for (int mm = 0; mm < 4; ++mm) {
        int row0 = bm + wr*64 + mm*16 + l4*4;
        #pragma unroll
        for (int nn = 0; nn < 4; ++nn) {
            int col = bn + wc*64 + nn*16 + l15;
            float bi = bias[col];
            #pragma unroll
            for (int r = 0; r < 4; ++r) {
                float v = acc[mm][nn][r] + bi;
                int row = row0 + r;
                size_t idx = (size_t)row * N + col;
                if (EPI == 2) {
                    ((float*)Cv)[idx] = v + res[idx];
                } else if (EPI == 1) {
                    v = 0.5f * v * (1.0f + erff(v * 0.70710678118654752f));
                    ((unsigned short*)Cv)[idx] = f2bf(v);
                } else { // EPI == 3
                    if (!isv) {
                        ((unsigned short*)Cv)[idx] = f2bf(v);
                    } else {
                        int bb = row >> 11, l = row & 2047;
                        int c2 = col - 2048, hh = c2 >> 6, dd = c2 & 63;
                        vt[((((size_t)(bb*HH + hh)*2 + (l & 1))*64 + dd) << 10) + (l >> 1)] = f2bf(v);
                    }
                }
            }
        }
    }
}

// ---------------------------------------------------------------- Attention
// Dilation-2 causal window == 2 independent causal sliding-window attentions
// (per parity), compressed length 1024, window 128 (+self). MFMA version:
// 1 wave/block, 64 queries x 64-key tiles. Swapped QK^T (mfma(K,Q)) puts each
// query's keys lane-local -> softmax = in-reg + shfl_xor(16/32) over l4
// groups. P re-fragments through an XOR-swizzled LDS buffer; PV uses
// pre-transposed V (vt) as the A-operand: O^T = V^T @ P^T-ish, all frags
// straight from global (L2-resident). fp32 softmax/accum throughout.
__global__ __launch_bounds__(64, 1) void mattn(
    const unsigned short* __restrict__ qkvb,  // [4096][3072] bf16 (Q at 0, K at +1024)
    const unsigned short* __restrict__ vt,    // [b][h][p][64][1024] bf16
    unsigned short* __restrict__ o)           // [4096][1024] bf16
{
    __shared__ __align__(16) unsigned char PlB[8192];     // P tile, swizzled
    int qt = blockIdx.x, p = blockIdx.y, bh = blockIdx.z;
    int b = bh >> 4, h = bh & 15;
    int lane = threadIdx.x;
    int l15 = lane & 15, l4 = lane >> 4;

    bf16x8 qf[4][2];
    #pragma unroll
    for (int qb = 0; qb < 4; ++qb) {
        int tq = qt*64 + qb*16 + l15;
        const unsigned short* qr = qkvb + (size_t)(b*LL + 2*tq + p)*3072 + h*64 + 8*l4;
        qf[qb][0] = *reinterpret_cast<const bf16x8*>(qr);
        qf[qb][1] = *reinterpret_cast<const bf16x8*>(qr + 32);
    }

    float mreg[4], lreg[4];
    #pragma unroll
    for (int qb = 0; qb < 4; ++qb) { mreg[qb] = -1e30f; lreg[qb] = 0.f; }
    f32x4 oac[4][4] = {};   // [mt=d-tile][qb], O^T layout

    const unsigned short* vbase = vt + ((size_t)((b*HH + h)*2 + p) << 16);

    int kt0 = qt - 2; if (kt0 < 0) kt0 = 0;
    for (int kt = kt0; kt <= qt; ++kt) {
        bf16x8 kf[4][2], vf[4][2];
        #pragma unroll
        for (int kb = 0; kb < 4; ++kb) {
            const unsigned short* kr = qkvb + (size_t)(b*LL + 2*(kt*64 + kb*16 + l15) + p)*3072 + 1024 + h*64 + 8*l4;
            kf[kb][0] = *reinterpret_cast<const bf16x8*>(kr);
            kf[kb][1] = *reinterpret_cast<const bf16x8*>(kr + 32);
        }
        #pragma unroll
        for (int mt = 0; mt < 4; ++mt) {
            const unsigned short* vr = vbase + (mt*16 + l15)*1024 + kt*64 + 8*l4;
            vf[mt][0] = *reinterpret_cast<const bf16x8*>(vr);
            vf[mt][1] = *reinterpret_cast<const bf16x8*>(vr + 32);
        }
        // S^T[k][q] = K @ Q^T : lane holds S[kt*64+kb*16+4*l4+r][qb*16+l15]
        f32x4 st[4][4];
        #pragma unroll
        for (int kb = 0; kb < 4; ++kb)
            #pragma unroll
            for (int qb = 0; qb < 4; ++qb) {
                f32x4 z = {0.f, 0.f, 0.f, 0.f};
                z = __builtin_amdgcn_mfma_f32_16x16x32_bf16(kf[kb][0], qf[qb][0], z, 0, 0, 0);
                st[kb][qb] = __builtin_amdgcn_mfma_f32_16x16x32_bf16(kf[kb][1], qf[qb][1], z, 0, 0, 0);
            }
        // online softmax per qb (per-lane 16 k's + 2-step shuffle over l4 groups)
        #pragma unroll
        for (int qb = 0; qb < 4; ++qb) {
            int tq = qt*64 + qb*16 + l15;
            int q = qb*16 + l15;
            float tmax = -1e30f;
            #pragma unroll
            for (int kb = 0; kb < 4; ++kb)
                #pragma unroll
                for (int r = 0; r < 4; ++r) {
                    int kc = kt*64 + kb*16 + 4*l4 + r;
                    float sv = st[kb][qb][r] * 0.125f;
                    sv = (kc + 128 >= tq && kc <= tq) ? sv : -1e30f;
                    st[kb][qb][r] = sv;
                    tmax = fmaxf(tmax, sv);
                }
            tmax = fmaxf(tmax, __shfl_xor(tmax, 16, 64));
            tmax = fmaxf(tmax, __shfl_xor(tmax, 32, 64));
            float newm = fmaxf(mreg[qb], tmax);
            float corr = __expf(mreg[qb] - newm);
            mreg[qb] = newm;
            float ps = 0.f;
            #pragma unroll
            for (int kb = 0; kb < 4; ++kb) {
                float p0 = __expf(st[kb][qb][0] - newm);
                float p1 = __expf(st[kb][qb][1] - newm);
                float p2 = __expf(st[kb][qb][2] - newm);
                float p3 = __expf(st[kb][qb][3] - newm);
                ps += (p0 + p1) + (p2 + p3);
                unsigned lo = (unsigned)f2bf(p0) | ((unsigned)f2bf(p1) << 16);
                unsigned hi = (unsigned)f2bf(p2) | ((unsigned)f2bf(p3) << 16);
                unsigned byteoff = ((unsigned)(q << 7) + (unsigned)(kb*32 + 8*l4)) ^ ((unsigned)(q & 7) << 4);
                *reinterpret_cast<uint2*>(PlB + byteoff) = make_uint2(lo, hi);
            }
            ps += __shfl_xor(ps, 16, 64);
            ps += __shfl_xor(ps, 32, 64);
            lreg[qb] = lreg[qb] * corr + ps;
            #pragma unroll
            for (int mt = 0; mt < 4; ++mt) {
                oac[mt][qb][0] *= corr; oac[mt][qb][1] *= corr;
                oac[mt][qb][2] *= corr; oac[mt][qb][3] *= corr;
            }
        }
        // PV: O^T[d][q] += V^T-frag x P-frag  (P re-read in B-frag layout)
        #pragma unroll
        for (int c = 0; c < 2; ++c)
            #pragma unroll
            for (int qb = 0; qb < 4; ++qb) {
                int q = qb*16 + l15;
                unsigned rb = ((unsigned)(q << 7) + (unsigned)(c*64 + 16*l4)) ^ ((unsigned)(q & 7) << 4);
                bf16x8 pf = *reinterpret_cast<const bf16x8*>(PlB + rb);
                #pragma unroll
                for (int mt = 0; mt < 4; ++mt)
                    oac[mt][qb] = __builtin_amdgcn_mfma_f32_16x16x32_bf16(vf[mt][c], pf, oac[mt][qb], 0, 0, 0);
            }
    }

    #pragma unroll
    for (int qb = 0; qb < 4; ++qb) {
        float inv = 1.f / lreg[qb];
        int tq = qt*64 + qb*16 + l15;
        unsigned short* orow = o + (size_t)(b*LL + 2*tq + p)*DD + h*64;
        #pragma unroll
        for (int mt = 0; mt < 4; ++mt) {
            int d0 = mt*16 + 4*l4;
            ushort4 o4;
            o4.x = f2bf(oac[mt][qb][0] * inv);
            o4.y = f2bf(oac[mt][qb][1] * inv);
            o4.z = f2bf(oac[mt][qb][2] * inv);
            o4.w = f2bf(oac[mt][qb][3] * inv);
            *reinterpret_cast<ushort4*>(orow + d0) = o4;
        }
    }
}

// ---------------------------------------------------------------- launch
extern "C" void kernel_launch(void* const* d_in, const int* in_sizes, int n_in,
                              void* d_out, int out_size, void* d_ws, size_t ws_size,
                              hipStream_t stream) {
    const float* x      = (const float*)d_in[0];
    const float* n1w    = (const float*)d_in[1];
    const float* n1b    = (const float*)d_in[2];
    const float* qkv_w  = (const float*)d_in[3];
    const float* qkv_b  = (const float*)d_in[4];
    const float* out_w  = (const float*)d_in[5];
    const float* out_b  = (const float*)d_in[6];
    const float* n2w    = (const float*)d_in[7];
    const float* n2b    = (const float*)d_in[8];
    const float* ffn_w1 = (const float*)d_in[9];
    const float* ffn_b1 = (const float*)d_in[10];
    const float* ffn_w2 = (const float*)d_in[11];
    const float* ffn_b2 = (const float*)d_in[12];

    unsigned char* wsb = (unsigned char*)d_ws;
    const size_t MB = 1024 * 1024;

    // ws layout (80MB):
    //  [0,24)  qkvb bf16  -+-> overlay after attn: mid bf16 [0,32)
    //  [24,32) vt bf16    -+
    //  [32,40) o_b bf16
    //  [40,48) xn bf16
    //  [48,56) hbuf bf16
    //  [56,80) weights bf16 transposed (qkvT 6, outT 2, w1T 8, w2T 8)
    unsigned short* qkvb = (unsigned short*)wsb;
    unsigned short* vt   = (unsigned short*)(wsb + 24*MB);
    unsigned short* mid  = (unsigned short*)wsb;
    unsigned short* o_b  = (unsigned short*)(wsb + 32*MB);
    unsigned short* xn   = (unsigned short*)(wsb + 40*MB);
    unsigned short* hbuf = (unsigned short*)(wsb + 48*MB);
    unsigned short* qkvT = (unsigned short*)(wsb + 56*MB);
    unsigned short* outT = (unsigned short*)(wsb + 62*MB);
    unsigned short* w1T  = (unsigned short*)(wsb + 64*MB);
    unsigned short* w2T  = (unsigned short*)(wsb + 72*MB);
    float*          y    = (float*)d_out;              // d_out doubles as y

    // 0. weight convert+transpose  fp32[K][N] -> bf16[N][K]
    convT_kernel<<<dim3(3*DD/64, DD/64), 256, 0, stream>>>(qkv_w,  qkvT, DD,  3*DD);
    convT_kernel<<<dim3(DD/64,   DD/64), 256, 0, stream>>>(out_w,  outT, DD,  DD);
    convT_kernel<<<dim3(HID/64,  DD/64), 256, 0, stream>>>(ffn_w1, w1T,  DD,  HID);
    convT_kernel<<<dim3(DD/64,  HID/64), 256, 0, stream>>>(ffn_w2, w2T,  HID, DD);

    // 1. xn = LN(x)                        (bf16)
    ln_kernel<<<MROWS, 256, 0, stream>>>(x, n1w, n1b, xn);
    // 2. qkv = xn @ qkv_w + qkv_b          (Q/K bf16 rowmajor, V -> vt)
    mgemm<3><<<(3*DD/128)*(MROWS/128), 256, 0, stream>>>(
        xn, qkvT, qkv_b, nullptr, qkvb, vt, MROWS, 3*DD, DD, 3*DD/128);
    // 3. o = dilated-window attention      (bf16, MFMA)
    mattn<<<dim3(16, 2, BB*HH), 64, 0, stream>>>(qkvb, vt, o_b);
    // 4. y = x + o @ out_w + out_b         (fp32, in d_out)
    mgemm<2><<<(DD/128)*(MROWS/128), 256, 0, stream>>>(
        o_b, outT, out_b, x, y, nullptr, MROWS, DD, DD, DD/128);
    // 5. h = LN(y)                         (bf16)
    ln_kernel<<<MROWS, 256, 0, stream>>>(y, n2w, n2b, hbuf);
    // 6. mid = gelu(h @ ffn_w1 + b1)       (bf16)
    mgemm<1><<<(HID/128)*(MROWS/128), 256, 0, stream>>>(
        hbuf, w1T, ffn_b1, nullptr, mid, nullptr, MROWS, HID, DD, HID/128);
    // 7. out = y + mid @ ffn_w2 + b2       (fp32, in-place over y)
    mgemm<2><<<(DD/128)*(MROWS/128), 256, 0, stream>>>(
        mid, w2T, ffn_b2, y, y, nullptr, MROWS, DD, HID, DD/128);
}

// Round 5
// 387.376 us; speedup vs baseline: 4.1180x; 1.0017x over previous
//
#include <hip/hip_runtime.h>
#include <math.h>

#define BB 2
#define LL 2048
#define DD 1024
#define HH 16
#define DH 64
#define HID 4096
#define MROWS (BB*LL)   // 4096

typedef __attribute__((ext_vector_type(8))) short bf16x8;
typedef __attribute__((ext_vector_type(4))) float f32x4;

__device__ __forceinline__ unsigned short f2bf(float f) {
    unsigned u = __builtin_bit_cast(unsigned, f);
    unsigned r = u + 0x7fffu + ((u >> 16) & 1u);
    return (unsigned short)(r >> 16);
}

__device__ __forceinline__ void ldsload16(const void* g, void* l) {
    __builtin_amdgcn_global_load_lds(
        (const __attribute__((address_space(1))) unsigned int*)g,
        (__attribute__((address_space(3))) unsigned int*)l,
        16, 0, 0);
}

// ------------------------------------------------- weight convert+transpose
// in: fp32 [K][N] row-major  ->  out: bf16 [N][K] row-major
__global__ __launch_bounds__(256) void convT_kernel(const float* __restrict__ in,
                                                    unsigned short* __restrict__ out,
                                                    int K, int N) {
    __shared__ float tile[64][65];
    int kt = blockIdx.y << 6, nt = blockIdx.x << 6;
    int t = threadIdx.x;
    int tr = t >> 4;            // 0..15
    int tc = (t & 15) << 2;     // 0,4,...,60
    #pragma unroll
    for (int i = 0; i < 4; ++i) {
        float4 v = *reinterpret_cast<const float4*>(&in[(size_t)(kt + i*16 + tr) * N + nt + tc]);
        tile[i*16 + tr][tc+0] = v.x;
        tile[i*16 + tr][tc+1] = v.y;
        tile[i*16 + tr][tc+2] = v.z;
        tile[i*16 + tr][tc+3] = v.w;
    }
    __syncthreads();
    #pragma unroll
    for (int i = 0; i < 4; ++i) {
        int n = i*16 + tr;
        ushort4 o4;
        o4.x = f2bf(tile[tc+0][n]);
        o4.y = f2bf(tile[tc+1][n]);
        o4.z = f2bf(tile[tc+2][n]);
        o4.w = f2bf(tile[tc+3][n]);
        *reinterpret_cast<ushort4*>(&out[(size_t)(nt + n) * K + kt + tc]) = o4;
    }
}

// ---------------------------------------------------------------- LayerNorm
// fp32 in -> bf16 out
__global__ __launch_bounds__(256) void ln_kernel(const float* __restrict__ in,
                                                 const float* __restrict__ w,
                                                 const float* __restrict__ b,
                                                 unsigned short* __restrict__ out) {
    int row = blockIdx.x;
    const float* x = in + (size_t)row * DD;
    unsigned short* o = out + (size_t)row * DD;
    int t = threadIdx.x;
    float4 v = reinterpret_cast<const float4*>(x)[t];
    float s  = v.x + v.y + v.z + v.w;
    float ss = v.x*v.x + v.y*v.y + v.z*v.z + v.w*v.w;
    #pragma unroll
    for (int off = 32; off > 0; off >>= 1) {
        s  += __shfl_down(s,  off, 64);
        ss += __shfl_down(ss, off, 64);
    }
    __shared__ float red[8];
    int wid = t >> 6, lane = t & 63;
    if (lane == 0) { red[wid] = s; red[4 + wid] = ss; }
    __syncthreads();
    if (t == 0) {
        float S  = red[0] + red[1] + red[2] + red[3];
        float SS = red[4] + red[5] + red[6] + red[7];
        float mean = S / DD;
        float var  = SS / DD - mean * mean;
        red[0] = mean;
        red[1] = rsqrtf(var + 1e-5f);
    }
    __syncthreads();
    float mean = red[0], rstd = red[1];
    float4 wv = reinterpret_cast<const float4*>(w)[t];
    float4 bv = reinterpret_cast<const float4*>(b)[t];
    ushort4 ov;
    ov.x = f2bf((v.x - mean) * rstd * wv.x + bv.x);
    ov.y = f2bf((v.y - mean) * rstd * wv.y + bv.y);
    ov.z = f2bf((v.z - mean) * rstd * wv.z + bv.z);
    ov.w = f2bf((v.w - mean) * rstd * wv.w + bv.w);
    reinterpret_cast<ushort4*>(o)[t] = ov;
}

// ------------------------------------------------------- MFMA GEMM (128x128)
// For N=1024 GEMMs (grid stays 256 blocks). EPI 2 = fp32 out + res.
// Triple-buffered, 2-deep prefetch, counted vmcnt. Fragment-linear LDS.
template<int EPI>
__global__ __launch_bounds__(256) void mgemm(
    const unsigned short* __restrict__ A,
    const unsigned short* __restrict__ WT,
    const float* __restrict__ bias,
    const float* res, void* Cv,
    int M, int N, int K, int nbx)
{
    __shared__ __align__(16) unsigned char smem[49152];   // 3 x (A 8KB + B 8KB)
    int bid = blockIdx.x;
    int nwg = gridDim.x;
    int cpx = nwg >> 3;                                   // grids %8 == 0
    int swz = (bid & 7) * cpx + (bid >> 3);               // XCD-aware swizzle
    int bn = (swz % nbx) * 128;
    int bm = (swz / nbx) * 128;
    int t = threadIdx.x, lane = t & 63, w = t >> 6;
    int wr = w >> 1, wc = w & 1;
    int l15 = lane & 15, l4 = lane >> 4;

    const unsigned short* Ap = A  + (size_t)(bm + w*32 + l15) * K + 8*l4;
    const unsigned short* Bp = WT + (size_t)(bn + w*32 + l15) * K + 8*l4;
    unsigned stoff = w*2048 + lane*16;

    f32x4 acc[4][4] = {};
    int nk = K >> 5;

    unsigned char* pb0 = smem;
    unsigned char* pb1 = smem + 16384;
    unsigned char* pb2 = smem + 32768;

    auto stage = [&](unsigned char* bs) {
        ldsload16(Ap,        bs + stoff);
        ldsload16(Ap + 16*K, bs + stoff + 1024);
        ldsload16(Bp,        bs + 8192 + stoff);
        ldsload16(Bp + 16*K, bs + 8192 + stoff + 1024);
        Ap += 32; Bp += 32;
    };

    stage(pb0);
    stage(pb1);

    for (int k = 0; k < nk; ++k) {
        if (k + 2 < nk) {
            stage(pb2);
            asm volatile("s_waitcnt vmcnt(8)\ns_barrier" ::: "memory");
        } else if (k + 2 == nk) {
            asm volatile("s_waitcnt vmcnt(4)\ns_barrier" ::: "memory");
        } else {
            asm volatile("s_waitcnt vmcnt(0)\ns_barrier" ::: "memory");
        }
        unsigned char* Asb = pb0;
        unsigned char* Bsb = pb0 + 8192;
        bf16x8 af[4], bfr[4];
        #pragma unroll
        for (int mm = 0; mm < 4; ++mm)
            af[mm] = *reinterpret_cast<const bf16x8*>(Asb + (wr*4 + mm)*1024 + lane*16);
        #pragma unroll
        for (int nn = 0; nn < 4; ++nn)
            bfr[nn] = *reinterpret_cast<const bf16x8*>(Bsb + (wc*4 + nn)*1024 + lane*16);
        #pragma unroll
        for (int mm = 0; mm < 4; ++mm)
            #pragma unroll
            for (int nn = 0; nn < 4; ++nn)
                acc[mm][nn] = __builtin_amdgcn_mfma_f32_16x16x32_bf16(af[mm], bfr[nn], acc[mm][nn], 0, 0, 0);
        asm volatile("s_waitcnt lgkmcnt(0)\ns_barrier" ::: "memory");
        unsigned char* tp = pb0; pb0 = pb1; pb1 = pb2; pb2 = tp;
    }

    #pragma unroll
    for (int mm = 0; mm < 4; ++mm) {
        int row0 = bm + wr*64 + mm*16 + l4*4;
        #pragma unroll
        for (int nn = 0; nn < 4; ++nn) {
            int col = bn + wc*64 + nn*16 + l15;
            float bi = bias[col];
            #pragma unroll
            for (int r = 0; r < 4; ++r) {
                float v = acc[mm][nn][r] + bi;
                size_t idx = (size_t)(row0 + r) * N + col;
                if (EPI == 2) {
                    ((float*)Cv)[idx] = v + res[idx];
                } else {
                    v = 0.5f * v * (1.0f + erff(v * 0.70710678118654752f));
                    ((unsigned short*)Cv)[idx] = f2bf(v);
                }
            }
        }
    }
}

// ------------------------------------------------------- MFMA GEMM (256x256)
// 8 waves (2Mx4N), BK=64, double-buffered 128KiB LDS, counted vmcnt(8).
// Per K-step/wave: 64 MFMA vs 24 ds_read_b128 + 8 global_load_lds.
// Fragment-linear LDS: A = 32 x 1KB blocks [kc][mtile], within block
// [l4 kslot][l15 row]*16B; stage dest and frag read are base + lane*16.
// EPI: 1 = GELU -> bf16; 3 = qkv (Q/K bf16 row-major, V -> vt transposed).
template<int EPI>
__global__ __launch_bounds__(512, 2) void mgemm256(
    const unsigned short* __restrict__ A,
    const unsigned short* __restrict__ WT,
    const float* __restrict__ bias,
    void* Cv,
    unsigned short* __restrict__ vt,
    int M, int N, int K, int nbx)
{
    __shared__ __align__(16) unsigned char smem[131072];  // 2 x (A 32KB + B 32KB)
    int bid = blockIdx.x;
    int nwg = gridDim.x;
    int cpx = nwg >> 3;                                   // grids %8 == 0
    int swz = (bid & 7) * cpx + (bid >> 3);               // XCD-aware swizzle
    int bn = (swz % nbx) * 256;
    int bm = (swz / nbx) * 256;
    int t = threadIdx.x, lane = t & 63, w = t >> 6;       // w: 0..7
    int wr = w >> 2, wc = w & 3;                          // 2 x 4 waves
    int l15 = lane & 15, l4 = lane >> 4;

    const unsigned short* Ap0 = A  + (size_t)(bm + w*16 + l15) * K + 8*l4;
    const unsigned short* Ap1 = Ap0 + (size_t)128 * K;
    const unsigned short* Bp0 = WT + (size_t)(bn + w*16 + l15) * K + 8*l4;
    const unsigned short* Bp1 = Bp0 + (size_t)128 * K;
    unsigned aoff = w*1024 + lane*16;
    int koff = 0;

    f32x4 acc[8][4] = {};
    int nk = K >> 6;

    auto stage = [&](int buf) {
        unsigned char* Asb = smem + (buf << 16);
        unsigned char* Bsb = Asb + 32768;
        ldsload16(Ap0 + koff,      Asb + aoff);
        ldsload16(Ap1 + koff,      Asb + aoff + 8192);
        ldsload16(Ap0 + koff + 32, Asb + aoff + 16384);
        ldsload16(Ap1 + koff + 32, Asb + aoff + 24576);
        ldsload16(Bp0 + koff,      Bsb + aoff);
        ldsload16(Bp1 + koff,      Bsb + aoff + 8192);
        ldsload16(Bp0 + koff + 32, Bsb + aoff + 16384);
        ldsload16(Bp1 + koff + 32, Bsb + aoff + 24576);
        koff += 64;
    };

    stage(0);
    for (int k = 0; k < nk; ++k) {
        if (k + 1 < nk) {
            stage((k + 1) & 1);
            asm volatile("s_waitcnt vmcnt(8)\ns_barrier" ::: "memory");
        } else {
            asm volatile("s_waitcnt vmcnt(0)\ns_barrier" ::: "memory");
        }
        unsigned char* Asb = smem + ((k & 1) << 16);
        unsigned char* Bsb = Asb + 32768;
        #pragma unroll
        for (int kc = 0; kc < 2; ++kc) {
            bf16x8 af[8], bfr[4];
            #pragma unroll
            for (int mm = 0; mm < 8; ++mm)
                af[mm] = *reinterpret_cast<const bf16x8*>(Asb + kc*16384 + (wr*8 + mm)*1024 + lane*16);
            #pragma unroll
            for (int nn = 0; nn < 4; ++nn)
                bfr[nn] = *reinterpret_cast<const bf16x8*>(Bsb + kc*16384 + (wc*4 + nn)*1024 + lane*16);
            #pragma unroll
            for (int mm = 0; mm < 8; ++mm)
                #pragma unroll
                for (int nn = 0; nn < 4; ++nn)
                    acc[mm][nn] = __builtin_amdgcn_mfma_f32_16x16x32_bf16(af[mm], bfr[nn], acc[mm][nn], 0, 0, 0);
        }
        asm volatile("s_waitcnt lgkmcnt(0)\ns_barrier" ::: "memory");
    }

    bool isv = (EPI == 3) && (bn >= 2048);
    #pragma unroll
    for (int mm = 0; mm < 8; ++mm) {
        int row0 = bm + wr*128 + mm*16 + l4*4;
        #pragma unroll
        for (int nn = 0; nn < 4; ++nn) {
            int col = bn + wc*64 + nn*16 + l15;
            float bi = bias[col];
            #pragma unroll
            for (int r = 0; r < 4; ++r) {
                float v = acc[mm][nn][r] + bi;
                int row = row0 + r;
                size_t idx = (size_t)row * N + col;
                if (EPI == 1) {
                    v = 0.5f * v * (1.0f + erff(v * 0.70710678118654752f));
                    ((unsigned short*)Cv)[idx] = f2bf(v);
                } else { // EPI == 3
                    if (!isv) {
                        ((unsigned short*)Cv)[idx] = f2bf(v);
                    } else {
                        int bb = row >> 11, l = row & 2047;
                        int c2 = col - 2048, hh = c2 >> 6, dd = c2 & 63;
                        vt[((((size_t)(bb*HH + hh)*2 + (l & 1))*64 + dd) << 10) + (l >> 1)] = f2bf(v);
                    }
                }
            }
        }
    }
}

// ---------------------------------------------------------------- Attention
// Dilation-2 causal window == 2 independent causal sliding-window attentions
// (per parity), compressed length 1024, window 128 (+self). MFMA, 1 wave/blk.
__global__ __launch_bounds__(64, 1) void mattn(
    const unsigned short* __restrict__ qkvb,  // [4096][3072] bf16
    const unsigned short* __restrict__ vt,    // [b][h][p][64][1024] bf16
    unsigned short* __restrict__ o)           // [4096][1024] bf16
{
    __shared__ __align__(16) unsigned char PlB[8192];     // P tile, swizzled
    int qt = blockIdx.x, p = blockIdx.y, bh = blockIdx.z;
    int b = bh >> 4, h = bh & 15;
    int lane = threadIdx.x;
    int l15 = lane & 15, l4 = lane >> 4;

    bf16x8 qf[4][2];
    #pragma unroll
    for (int qb = 0; qb < 4; ++qb) {
        int tq = qt*64 + qb*16 + l15;
        const unsigned short* qr = qkvb + (size_t)(b*LL + 2*tq + p)*3072 + h*64 + 8*l4;
        qf[qb][0] = *reinterpret_cast<const bf16x8*>(qr);
        qf[qb][1] = *reinterpret_cast<const bf16x8*>(qr + 32);
    }

    float mreg[4], lreg[4];
    #pragma unroll
    for (int qb = 0; qb < 4; ++qb) { mreg[qb] = -1e30f; lreg[qb] = 0.f; }
    f32x4 oac[4][4] = {};   // [mt=d-tile][qb], O^T layout

    const unsigned short* vbase = vt + ((size_t)((b*HH + h)*2 + p) << 16);

    int kt0 = qt - 2; if (kt0 < 0) kt0 = 0;
    for (int kt = kt0; kt <= qt; ++kt) {
        bf16x8 kf[4][2], vf[4][2];
        #pragma unroll
        for (int kb = 0; kb < 4; ++kb) {
            const unsigned short* kr = qkvb + (size_t)(b*LL + 2*(kt*64 + kb*16 + l15) + p)*3072 + 1024 + h*64 + 8*l4;
            kf[kb][0] = *reinterpret_cast<const bf16x8*>(kr);
            kf[kb][1] = *reinterpret_cast<const bf16x8*>(kr + 32);
        }
        #pragma unroll
        for (int mt = 0; mt < 4; ++mt) {
            const unsigned short* vr = vbase + (mt*16 + l15)*1024 + kt*64 + 8*l4;
            vf[mt][0] = *reinterpret_cast<const bf16x8*>(vr);
            vf[mt][1] = *reinterpret_cast<const bf16x8*>(vr + 32);
        }
        f32x4 st[4][4];
        #pragma unroll
        for (int kb = 0; kb < 4; ++kb)
            #pragma unroll
            for (int qb = 0; qb < 4; ++qb) {
                f32x4 z = {0.f, 0.f, 0.f, 0.f};
                z = __builtin_amdgcn_mfma_f32_16x16x32_bf16(kf[kb][0], qf[qb][0], z, 0, 0, 0);
                st[kb][qb] = __builtin_amdgcn_mfma_f32_16x16x32_bf16(kf[kb][1], qf[qb][1], z, 0, 0, 0);
            }
        #pragma unroll
        for (int qb = 0; qb < 4; ++qb) {
            int tq = qt*64 + qb*16 + l15;
            int q = qb*16 + l15;
            float tmax = -1e30f;
            #pragma unroll
            for (int kb = 0; kb < 4; ++kb)
                #pragma unroll
                for (int r = 0; r < 4; ++r) {
                    int kc = kt*64 + kb*16 + 4*l4 + r;
                    float sv = st[kb][qb][r] * 0.125f;
                    sv = (kc + 128 >= tq && kc <= tq) ? sv : -1e30f;
                    st[kb][qb][r] = sv;
                    tmax = fmaxf(tmax, sv);
                }
            tmax = fmaxf(tmax, __shfl_xor(tmax, 16, 64));
            tmax = fmaxf(tmax, __shfl_xor(tmax, 32, 64));
            float newm = fmaxf(mreg[qb], tmax);
            float corr = __expf(mreg[qb] - newm);
            mreg[qb] = newm;
            float ps = 0.f;
            #pragma unroll
            for (int kb = 0; kb < 4; ++kb) {
                float p0 = __expf(st[kb][qb][0] - newm);
                float p1 = __expf(st[kb][qb][1] - newm);
                float p2 = __expf(st[kb][qb][2] - newm);
                float p3 = __expf(st[kb][qb][3] - newm);
                ps += (p0 + p1) + (p2 + p3);
                unsigned lo = (unsigned)f2bf(p0) | ((unsigned)f2bf(p1) << 16);
                unsigned hi = (unsigned)f2bf(p2) | ((unsigned)f2bf(p3) << 16);
                unsigned byteoff = ((unsigned)(q << 7) + (unsigned)(kb*32 + 8*l4)) ^ ((unsigned)(q & 7) << 4);
                *reinterpret_cast<uint2*>(PlB + byteoff) = make_uint2(lo, hi);
            }
            ps += __shfl_xor(ps, 16, 64);
            ps += __shfl_xor(ps, 32, 64);
            lreg[qb] = lreg[qb] * corr + ps;
            #pragma unroll
            for (int mt = 0; mt < 4; ++mt) {
                oac[mt][qb][0] *= corr; oac[mt][qb][1] *= corr;
                oac[mt][qb][2] *= corr; oac[mt][qb][3] *= corr;
            }
        }
        #pragma unroll
        for (int c = 0; c < 2; ++c)
            #pragma unroll
            for (int qb = 0; qb < 4; ++qb) {
                int q = qb*16 + l15;
                unsigned rb = ((unsigned)(q << 7) + (unsigned)(c*64 + 16*l4)) ^ ((unsigned)(q & 7) << 4);
                bf16x8 pf = *reinterpret_cast<const bf16x8*>(PlB + rb);
                #pragma unroll
                for (int mt = 0; mt < 4; ++mt)
                    oac[mt][qb] = __builtin_amdgcn_mfma_f32_16x16x32_bf16(vf[mt][c], pf, oac[mt][qb], 0, 0, 0);
            }
    }

    #pragma unroll
    for (int qb = 0; qb < 4; ++qb) {
        float inv = 1.f / lreg[qb];
        int tq = qt*64 + qb*16 + l15;
        unsigned short* orow = o + (size_t)(b*LL + 2*tq + p)*DD + h*64;
        #pragma unroll
        for (int mt = 0; mt < 4; ++mt) {
            int d0 = mt*16 + 4*l4;
            ushort4 o4;
            o4.x = f2bf(oac[mt][qb][0] * inv);
            o4.y = f2bf(oac[mt][qb][1] * inv);
            o4.z = f2bf(oac[mt][qb][2] * inv);
            o4.w = f2bf(oac[mt][qb][3] * inv);
            *reinterpret_cast<ushort4*>(orow + d0) = o4;
        }
    }
}

// ---------------------------------------------------------------- launch
extern "C" void kernel_launch(void* const* d_in, const int* in_sizes, int n_in,
                              void* d_out, int out_size, void* d_ws, size_t ws_size,
                              hipStream_t stream) {
    const float* x      = (const float*)d_in[0];
    const float* n1w    = (const float*)d_in[1];
    const float* n1b    = (const float*)d_in[2];
    const float* qkv_w  = (const float*)d_in[3];
    const float* qkv_b  = (const float*)d_in[4];
    const float* out_w  = (const float*)d_in[5];
    const float* out_b  = (const float*)d_in[6];
    const float* n2w    = (const float*)d_in[7];
    const float* n2b    = (const float*)d_in[8];
    const float* ffn_w1 = (const float*)d_in[9];
    const float* ffn_b1 = (const float*)d_in[10];
    const float* ffn_w2 = (const float*)d_in[11];
    const float* ffn_b2 = (const float*)d_in[12];

    unsigned char* wsb = (unsigned char*)d_ws;
    const size_t MB = 1024 * 1024;

    // ws layout (80MB):
    //  [0,24)  qkvb bf16  -+-> overlay after attn: mid bf16 [0,32)
    //  [24,32) vt bf16    -+
    //  [32,40) o_b bf16
    //  [40,48) xn bf16
    //  [48,56) hbuf bf16
    //  [56,80) weights bf16 transposed (qkvT 6, outT 2, w1T 8, w2T 8)
    unsigned short* qkvb = (unsigned short*)wsb;
    unsigned short* vt   = (unsigned short*)(wsb + 24*MB);
    unsigned short* mid  = (unsigned short*)wsb;
    unsigned short* o_b  = (unsigned short*)(wsb + 32*MB);
    unsigned short* xn   = (unsigned short*)(wsb + 40*MB);
    unsigned short* hbuf = (unsigned short*)(wsb + 48*MB);
    unsigned short* qkvT = (unsigned short*)(wsb + 56*MB);
    unsigned short* outT = (unsigned short*)(wsb + 62*MB);
    unsigned short* w1T  = (unsigned short*)(wsb + 64*MB);
    unsigned short* w2T  = (unsigned short*)(wsb + 72*MB);
    float*          y    = (float*)d_out;              // d_out doubles as y

    // 0. weight convert+transpose  fp32[K][N] -> bf16[N][K]
    convT_kernel<<<dim3(3*DD/64, DD/64), 256, 0, stream>>>(qkv_w,  qkvT, DD,  3*DD);
    convT_kernel<<<dim3(DD/64,   DD/64), 256, 0, stream>>>(out_w,  outT, DD,  DD);
    convT_kernel<<<dim3(HID/64,  DD/64), 256, 0, stream>>>(ffn_w1, w1T,  DD,  HID);
    convT_kernel<<<dim3(DD/64,  HID/64), 256, 0, stream>>>(ffn_w2, w2T,  HID, DD);

    // 1. xn = LN(x)                        (bf16)
    ln_kernel<<<MROWS, 256, 0, stream>>>(x, n1w, n1b, xn);
    // 2. qkv = xn @ qkv_w + qkv_b          (Q/K bf16 rowmajor, V -> vt)  [256²]
    mgemm256<3><<<(3*DD/256)*(MROWS/256), 512, 0, stream>>>(
        xn, qkvT, qkv_b, qkvb, vt, MROWS, 3*DD, DD, 3*DD/256);
    // 3. o = dilated-window attention      (bf16, MFMA)
    mattn<<<dim3(16, 2, BB*HH), 64, 0, stream>>>(qkvb, vt, o_b);
    // 4. y = x + o @ out_w + out_b         (fp32, in d_out)  [128²]
    mgemm<2><<<(DD/128)*(MROWS/128), 256, 0, stream>>>(
        o_b, outT, out_b, x, y, MROWS, DD, DD, DD/128);
    // 5. h = LN(y)                         (bf16)
    ln_kernel<<<MROWS, 256, 0, stream>>>(y, n2w, n2b, hbuf);
    // 6. mid = gelu(h @ ffn_w1 + b1)       (bf16)  [256²]
    mgemm256<1><<<(HID/256)*(MROWS/256), 512, 0, stream>>>(
        hbuf, w1T, ffn_b1, mid, nullptr, MROWS, HID, DD, HID/256);
    // 7. out = y + mid @ ffn_w2 + b2       (fp32, in-place over y)  [128²]
    mgemm<2><<<(DD/128)*(MROWS/128), 256, 0, stream>>>(
        mid, w2T, ffn_b2, y, y, MROWS, DD, HID, DD/128);
}